// Round 2
// baseline (552.565 us; speedup 1.0000x reference)
//
#include <hip/hip_runtime.h>
#include <cstdint>
#include <cstddef>

typedef __attribute__((ext_vector_type(8))) short short8;
typedef __attribute__((ext_vector_type(4))) float floatx4;
typedef __attribute__((ext_vector_type(4))) short short4v;
typedef unsigned short u16;

#define B_   2
#define T_   2048
#define D_   1024
#define H_   16
#define HKV_ 4
#define HD_  64
#define KV_  256
#define M_   4096  // B*T

__device__ __forceinline__ float b2f(u16 u) {
    union { unsigned int i; float f; } v; v.i = ((unsigned int)u) << 16; return v.f;
}
__device__ __forceinline__ u16 f2b(float f) {
    union { float f; unsigned int i; } v; v.f = f;
    unsigned int r = v.i + 0x7FFF + ((v.i >> 16) & 1);
    return (u16)(r >> 16);
}

// ---------------------------------------------------------------------------
// fp32 -> bf16 (RNE) cast, 4 elements/thread.
// ---------------------------------------------------------------------------
__global__ __launch_bounds__(256) void castk(const float* __restrict__ in,
                                             u16* __restrict__ out, int n) {
    int i = (blockIdx.x * 256 + threadIdx.x) * 4;
    if (i >= n) return;
    float4 v = *(const float4*)(in + i);
    short4v o;
    o.x = (short)f2b(v.x); o.y = (short)f2b(v.y);
    o.z = (short)f2b(v.z); o.w = (short)f2b(v.w);
    *(short4v*)(out + i) = o;
}

// ---------------------------------------------------------------------------
// GEMM: C[M,N] = A[M,K] * W[N,K]^T   (bf16 in, fp32 acc, OutT out)
// 64x64 block tile, 4 waves (each wave: 16 rows x 64 cols), no LDS.
// MFMA 16x16x32 bf16 layouts (verified m89/m91/m97):
//   A-frag: lane holds A[m0 + (lane&15)][k0 + (lane>>4)*8 + j], j=0..7
//   B-frag: lane holds W[n0 + (lane&15)][k0 + (lane>>4)*8 + j]  (= B^T[k][n])
//   C/D:    col = lane&15, row = (lane>>4)*4 + reg
// ---------------------------------------------------------------------------
template <typename OutT>
__global__ __launch_bounds__(256) void gemm_bt(const u16* __restrict__ A,
                                               const u16* __restrict__ W,
                                               OutT* __restrict__ C,
                                               int M, int N, int K) {
    const int wave = threadIdx.x >> 6;
    const int lane = threadIdx.x & 63;
    const int quad = lane >> 4;
    const int l16  = lane & 15;
    const int m0 = blockIdx.y * 64 + wave * 16;
    const int n0 = blockIdx.x * 64;

    floatx4 acc[4];
#pragma unroll
    for (int i = 0; i < 4; i++) acc[i] = (floatx4){0.f, 0.f, 0.f, 0.f};

    const u16* ap = A + (size_t)(m0 + l16) * K + quad * 8;
    const u16* wp = W + (size_t)(n0 + l16) * K + quad * 8;

    for (int k = 0; k < K; k += 32) {
        short8 af = *(const short8*)(ap + k);
#pragma unroll
        for (int ct = 0; ct < 4; ct++) {
            short8 bfr = *(const short8*)(wp + (size_t)ct * 16 * K + k);
            acc[ct] = __builtin_amdgcn_mfma_f32_16x16x32_bf16(af, bfr, acc[ct], 0, 0, 0);
        }
    }
#pragma unroll
    for (int ct = 0; ct < 4; ct++)
#pragma unroll
        for (int r = 0; r < 4; r++) {
            float val = acc[ct][r];
            size_t idx = (size_t)(m0 + quad * 4 + r) * N + n0 + ct * 16 + l16;
            if constexpr (sizeof(OutT) == 4) C[idx] = val;
            else                             C[idx] = (OutT)f2b(val);
        }
}

// ---------------------------------------------------------------------------
// Fused per-head RMSNorm + RoPE (+ q_gain and 1/sqrt(hd) folded into Q).
// One wave per (token-row, head). In-place on Qb and Kb (bf16).
// Tasks [0, M_*H_): Q;  [M_*H_, M_*H_ + M_*HKV_): K.
// ---------------------------------------------------------------------------
__global__ __launch_bounds__(256) void norm_rope(u16* __restrict__ Qb,
                                                 u16* __restrict__ Kb,
                                                 const float* __restrict__ gain) {
    const int task = blockIdx.x * 4 + (threadIdx.x >> 6);
    const int lane = threadIdx.x & 63;

    u16* ptr; float gs; int t;
    if (task < M_ * H_) {
        int row = task >> 4, h = task & 15;
        ptr = Qb + (size_t)row * D_ + h * HD_;
        gs  = gain[h] * 0.125f;               // q_gain * 1/sqrt(64) (exact exp shift)
        t   = row & (T_ - 1);
    } else {
        int k = task - M_ * H_;
        int row = k >> 2, h = k & 3;
        ptr = Kb + (size_t)row * KV_ + h * HD_;
        gs  = 1.0f;
        t   = row & (T_ - 1);
    }

    float v = b2f(ptr[lane]);
    float ss = v * v;
#pragma unroll
    for (int off = 32; off; off >>= 1) ss += __shfl_xor(ss, off);
    float inv = rsqrtf(ss * (1.0f / 64.0f) + 1.1920929e-7f);  // fp32 eps
    v *= inv;

    const int i = lane & 31;
    float freq = powf(10000.0f, -(float)i * (1.0f / 32.0f));
    float ang  = (float)t * freq;
    float c = cosf(ang), s = sinf(ang);
    float other = __shfl_xor(v, 32);
    // out[:32] = x1*c + x2*s ; out[32:] = -x1*s + x2*c
    float out = (lane < 32) ? (v * c + other * s) : (v * c - other * s);
    ptr[lane] = f2b(out * gs);
}

// ---------------------------------------------------------------------------
// V transpose: Vb[(b*T+t)*KV_ + g*64 + d] -> Vt[((b*4+g)*64 + d)*T_ + t]
// ---------------------------------------------------------------------------
__global__ __launch_bounds__(256) void vtrans(const u16* __restrict__ Vb,
                                              u16* __restrict__ Vt) {
    int idx = blockIdx.x * 256 + threadIdx.x;  // 0 .. M_*KV_-1
    int t    = idx & (T_ - 1);
    int rest = idx >> 11;        // (b*4+g)*64 + d
    int d    = rest & 63;
    int gb   = rest >> 6;        // b*4+g
    int b    = gb >> 2, g = gb & 3;
    Vt[idx] = Vb[(size_t)(b * T_ + t) * KV_ + g * 64 + d];
}

// ---------------------------------------------------------------------------
// Flash attention (causal). 1 wave per (b, h, 16-query tile).
// 32-key tiles: S (16x32) via 4 MFMAs, online softmax (quad shuffle-reduce),
// P through LDS (C/D layout -> A layout, m120-verified), PV via 4 MFMAs, V^T.
// Q is pre-scaled by q_gain/8.
// ---------------------------------------------------------------------------
__global__ __launch_bounds__(64) void flash(const u16* __restrict__ Qb,
                                            const u16* __restrict__ Kb,
                                            const u16* __restrict__ Vt,
                                            u16* __restrict__ Y) {
    const int tq = blockIdx.x;      // 0..T_/16-1
    const int h  = blockIdx.y;      // 0..15
    const int b  = blockIdx.z;      // 0..1
    const int g  = h >> 2;          // kv head (rep=4)
    const int lane = threadIdx.x;
    const int quad = lane >> 4, l16 = lane & 15;

    __shared__ u16 P[16][40];       // 32 cols + 8 pad

    const u16* qp = Qb + (size_t)(b * T_ + tq * 16 + l16) * D_ + h * HD_ + quad * 8;
    short8 aq0 = *(const short8*)(qp);
    short8 aq1 = *(const short8*)(qp + 32);

    floatx4 acc[4];
#pragma unroll
    for (int i = 0; i < 4; i++) acc[i] = (floatx4){0.f, 0.f, 0.f, 0.f};
    float mrow[4] = {-INFINITY, -INFINITY, -INFINITY, -INFINITY};
    float lrow[4] = {0.f, 0.f, 0.f, 0.f};

    const u16* kp = Kb + (size_t)(b * T_ + l16) * KV_ + g * HD_ + quad * 8;
    const u16* vp = Vt + (size_t)((b * 4 + g) * HD_ + l16) * T_ + quad * 8;

    const int ntiles = (tq * 16 + 47) >> 5;
    for (int tk = 0; tk < ntiles; tk++) {
        const u16* kt = kp + (size_t)tk * 32 * KV_;
        short8 bk00 = *(const short8*)(kt);
        short8 bk01 = *(const short8*)(kt + 32);
        short8 bk10 = *(const short8*)(kt + 16 * KV_);
        short8 bk11 = *(const short8*)(kt + 16 * KV_ + 32);

        floatx4 S0 = (floatx4){0.f, 0.f, 0.f, 0.f};
        floatx4 S1 = (floatx4){0.f, 0.f, 0.f, 0.f};
        S0 = __builtin_amdgcn_mfma_f32_16x16x32_bf16(aq0, bk00, S0, 0, 0, 0);
        S0 = __builtin_amdgcn_mfma_f32_16x16x32_bf16(aq1, bk01, S0, 0, 0, 0);
        S1 = __builtin_amdgcn_mfma_f32_16x16x32_bf16(aq0, bk10, S1, 0, 0, 0);
        S1 = __builtin_amdgcn_mfma_f32_16x16x32_bf16(aq1, bk11, S1, 0, 0, 0);

        const int key0 = tk * 32 + l16, key1 = key0 + 16;
#pragma unroll
        for (int r = 0; r < 4; r++) {
            int row = tq * 16 + quad * 4 + r;
            float s0 = (key0 <= row) ? S0[r] : -INFINITY;
            float s1 = (key1 <= row) ? S1[r] : -INFINITY;
            float mx = fmaxf(s0, s1);
#pragma unroll
            for (int off = 1; off < 16; off <<= 1) mx = fmaxf(mx, __shfl_xor(mx, off));
            float mnew = fmaxf(mrow[r], mx);
            float al = __expf(mrow[r] - mnew);
            float p0 = __expf(s0 - mnew);
            float p1 = __expf(s1 - mnew);
            float ps = p0 + p1;
#pragma unroll
            for (int off = 1; off < 16; off <<= 1) ps += __shfl_xor(ps, off);
            lrow[r] = lrow[r] * al + ps;
            mrow[r] = mnew;
            acc[0][r] *= al; acc[1][r] *= al; acc[2][r] *= al; acc[3][r] *= al;
            P[quad * 4 + r][l16]      = f2b(p0);
            P[quad * 4 + r][16 + l16] = f2b(p1);
        }
        __syncthreads();
        short8 pf = *(const short8*)&P[l16][quad * 8];
        const u16* vt2 = vp + tk * 32;
#pragma unroll
        for (int dd = 0; dd < 4; dd++) {
            short8 bv = *(const short8*)(vt2 + (size_t)dd * 16 * T_);
            acc[dd] = __builtin_amdgcn_mfma_f32_16x16x32_bf16(pf, bv, acc[dd], 0, 0, 0);
        }
        __syncthreads();
    }

#pragma unroll
    for (int r = 0; r < 4; r++) {
        float invl = 1.0f / lrow[r];
        int t = tq * 16 + quad * 4 + r;
        u16* yp = Y + (size_t)(b * T_ + t) * D_ + h * HD_ + l16;
#pragma unroll
        for (int dd = 0; dd < 4; dd++)
            yp[dd * 16] = f2b(acc[dd][r] * invl);
    }
}

// ---------------------------------------------------------------------------
extern "C" void kernel_launch(void* const* d_in, const int* in_sizes, int n_in,
                              void* d_out, int out_size, void* d_ws, size_t ws_size,
                              hipStream_t stream) {
    const float* x    = (const float*)d_in[0];
    const float* Wq   = (const float*)d_in[1];
    const float* Wk   = (const float*)d_in[2];
    const float* Wv   = (const float*)d_in[3];
    const float* Wp   = (const float*)d_in[4];
    const float* gain = (const float*)d_in[5];
    float* out = (float*)d_out;

    u16* xb  = (u16*)d_ws;                    // 4M
    u16* Wqb = xb  + (size_t)M_ * D_;         // 1M
    u16* Wkb = Wqb + (size_t)D_ * D_;         // 256K
    u16* Wvb = Wkb + (size_t)KV_ * D_;        // 256K
    u16* Wpb = Wvb + (size_t)KV_ * D_;        // 1M
    u16* Qb  = Wpb + (size_t)D_ * D_;         // 4M
    u16* Kb  = Qb  + (size_t)M_ * D_;         // 1M
    u16* Vb  = Kb  + (size_t)M_ * KV_;        // 1M
    u16* Vt  = Vb  + (size_t)M_ * KV_;        // 1M
    u16* Y   = Vt  + (size_t)M_ * KV_;        // 4M   (total 35 MB)

    castk<<<(M_ * D_) / 1024, 256, 0, stream>>>(x,  xb,  M_ * D_);
    castk<<<(D_ * D_) / 1024, 256, 0, stream>>>(Wq, Wqb, D_ * D_);
    castk<<<(KV_ * D_) / 1024, 256, 0, stream>>>(Wk, Wkb, KV_ * D_);
    castk<<<(KV_ * D_) / 1024, 256, 0, stream>>>(Wv, Wvb, KV_ * D_);
    castk<<<(D_ * D_) / 1024, 256, 0, stream>>>(Wp, Wpb, D_ * D_);

    gemm_bt<u16><<<dim3(D_ / 64, M_ / 64), 256, 0, stream>>>(xb, Wqb, Qb, M_, D_, D_);
    gemm_bt<u16><<<dim3(KV_ / 64, M_ / 64), 256, 0, stream>>>(xb, Wkb, Kb, M_, KV_, D_);
    gemm_bt<u16><<<dim3(KV_ / 64, M_ / 64), 256, 0, stream>>>(xb, Wvb, Vb, M_, KV_, D_);

    norm_rope<<<(M_ * H_ + M_ * HKV_) / 4, 256, 0, stream>>>(Qb, Kb, gain);
    vtrans<<<(M_ * KV_) / 256, 256, 0, stream>>>(Vb, Vt);

    flash<<<dim3(T_ / 16, H_, B_), 64, 0, stream>>>(Qb, Kb, Vt, Y);

    gemm_bt<float><<<dim3(D_ / 64, M_ / 64), 256, 0, stream>>>(Y, Wpb, out, M_, D_, D_);
}

// Round 3
// 396.853 us; speedup vs baseline: 1.3924x; 1.3924x over previous
//
#include <hip/hip_runtime.h>
#include <cstdint>
#include <cstddef>

typedef __attribute__((ext_vector_type(8))) short short8;
typedef __attribute__((ext_vector_type(4))) float floatx4;
typedef __attribute__((ext_vector_type(4))) short short4v;
typedef unsigned short u16;

#define B_   2
#define T_   2048
#define D_   1024
#define H_   16
#define HKV_ 4
#define HD_  64
#define KV_  256
#define M_   4096   // B*T
#define QS_  1536   // fused QKV row stride (1024 Q + 256 K + 256 V)

__device__ __forceinline__ float b2f(u16 u) {
    union { unsigned int i; float f; } v; v.i = ((unsigned int)u) << 16; return v.f;
}
__device__ __forceinline__ u16 f2b(float f) {
    union { float f; unsigned int i; } v; v.f = f;
    unsigned int r = v.i + 0x7FFF + ((v.i >> 16) & 1);
    return (u16)(r >> 16);
}

// async global->LDS, 16 bytes per lane (global_load_lds_dwordx4)
__device__ __forceinline__ void async16(const u16* g, u16* l) {
    __builtin_amdgcn_global_load_lds(
        (const __attribute__((address_space(1))) unsigned int*)g,
        (__attribute__((address_space(3))) unsigned int*)l, 16, 0, 0);
}

// ---------------------------------------------------------------------------
// fp32 -> bf16 (RNE) cast, 4 elements/thread.
// ---------------------------------------------------------------------------
__global__ __launch_bounds__(256) void castk(const float* __restrict__ in,
                                             u16* __restrict__ out, int n) {
    int i = (blockIdx.x * 256 + threadIdx.x) * 4;
    if (i >= n) return;
    float4 v = *(const float4*)(in + i);
    short4v o;
    o.x = (short)f2b(v.x); o.y = (short)f2b(v.y);
    o.z = (short)f2b(v.z); o.w = (short)f2b(v.w);
    *(short4v*)(out + i) = o;
}

// ---------------------------------------------------------------------------
// m97-style GEMM: C[M,N] = A[M,K] * W[N,K]^T  (bf16 in, fp32 acc, OutT out)
// 128x128 block tile, BK=32, 4 waves (2x2 of 64x64), single-buffered LDS via
// global_load_lds width=16, 2-barrier K-loop.  ldc = output row stride.
// ---------------------------------------------------------------------------
template <typename OutT>
__global__ __launch_bounds__(256) void gemm128(const u16* __restrict__ A,
                                               const u16* __restrict__ W,
                                               OutT* __restrict__ C,
                                               int M, int N, int K, int ldc) {
    __shared__ u16 As[128 * 32];
    __shared__ u16 Bs[128 * 32];
    const int t = threadIdx.x;
    const int wave = t >> 6, lane = t & 63;
    const int quad = lane >> 4, l16 = lane & 15;
    const int wm = (wave >> 1) * 64, wn = (wave & 1) * 64;
    const int m0 = blockIdx.y * 128, n0 = blockIdx.x * 128;

    floatx4 acc[4][4];
#pragma unroll
    for (int i = 0; i < 4; i++)
#pragma unroll
        for (int j = 0; j < 4; j++) acc[i][j] = (floatx4){0.f, 0.f, 0.f, 0.f};

    const int sr = t >> 2, sc = (t & 3) * 8;     // staging row/col for this thread
    const u16* ga = A + (size_t)(m0 + sr) * K + sc;
    const u16* gb = W + (size_t)(n0 + sr) * K + sc;
    u16* lA = As + t * 8;                        // byte offset t*16
    u16* lB = Bs + t * 8;

    // stage tile k=0
    async16(ga, lA);
    async16(ga + (size_t)64 * K, lA + 64 * 32);
    async16(gb, lB);
    async16(gb + (size_t)64 * K, lB + 64 * 32);

    for (int kt = 0; kt < K; kt += 32) {
        __syncthreads();                         // staging complete
        short8 af[4], bf[4];
#pragma unroll
        for (int mt = 0; mt < 4; mt++)
            af[mt] = *(const short8*)(As + (wm + mt * 16 + l16) * 32 + quad * 8);
#pragma unroll
        for (int nt = 0; nt < 4; nt++)
            bf[nt] = *(const short8*)(Bs + (wn + nt * 16 + l16) * 32 + quad * 8);
#pragma unroll
        for (int mt = 0; mt < 4; mt++)
#pragma unroll
            for (int nt = 0; nt < 4; nt++)
                acc[mt][nt] = __builtin_amdgcn_mfma_f32_16x16x32_bf16(
                    af[mt], bf[nt], acc[mt][nt], 0, 0, 0);
        __syncthreads();                         // all waves done with LDS
        if (kt + 32 < K) {
            const u16* ga2 = ga + kt + 32;
            const u16* gb2 = gb + kt + 32;
            async16(ga2, lA);
            async16(ga2 + (size_t)64 * K, lA + 64 * 32);
            async16(gb2, lB);
            async16(gb2 + (size_t)64 * K, lB + 64 * 32);
        }
    }

#pragma unroll
    for (int mt = 0; mt < 4; mt++)
#pragma unroll
        for (int nt = 0; nt < 4; nt++)
#pragma unroll
            for (int r = 0; r < 4; r++) {
                int row = m0 + wm + mt * 16 + quad * 4 + r;
                int col = n0 + wn + nt * 16 + l16;
                float val = acc[mt][nt][r];
                if constexpr (sizeof(OutT) == 4) C[(size_t)row * ldc + col] = val;
                else                             C[(size_t)row * ldc + col] = (OutT)f2b(val);
            }
}

// ---------------------------------------------------------------------------
// Fused per-head RMSNorm + RoPE (+ q_gain and 1/sqrt(hd) folded into Q).
// Operates in-place on the fused QKV buffer (row stride QS_).
// Tasks [0, M_*H_): Q;  [M_*H_, M_*H_ + M_*HKV_): K.
// ---------------------------------------------------------------------------
__global__ __launch_bounds__(256) void norm_rope(u16* __restrict__ QKV,
                                                 const float* __restrict__ gain) {
    const int task = blockIdx.x * 4 + (threadIdx.x >> 6);
    const int lane = threadIdx.x & 63;

    u16* ptr; float gs; int t;
    if (task < M_ * H_) {
        int row = task >> 4, h = task & 15;
        ptr = QKV + (size_t)row * QS_ + h * HD_;
        gs  = gain[h] * 0.125f;               // q_gain * 1/sqrt(64)
        t   = row & (T_ - 1);
    } else {
        int k = task - M_ * H_;
        int row = k >> 2, h = k & 3;
        ptr = QKV + (size_t)row * QS_ + D_ + h * HD_;
        gs  = 1.0f;
        t   = row & (T_ - 1);
    }

    float v = b2f(ptr[lane]);
    float ss = v * v;
#pragma unroll
    for (int off = 32; off; off >>= 1) ss += __shfl_xor(ss, off);
    float inv = rsqrtf(ss * (1.0f / 64.0f) + 1.1920929e-7f);
    v *= inv;

    const int i = lane & 31;
    float freq = powf(10000.0f, -(float)i * (1.0f / 32.0f));
    float ang  = (float)t * freq;
    float c = cosf(ang), s = sinf(ang);
    float other = __shfl_xor(v, 32);
    float out = (lane < 32) ? (v * c + other * s) : (v * c - other * s);
    ptr[lane] = f2b(out * gs);
}

// ---------------------------------------------------------------------------
// V transpose from fused QKV: QKV[row*QS_ + 1280 + g*64 + d] ->
//   Vt[((b*4+g)*64 + d)*T_ + t],  row = b*T_+t
// ---------------------------------------------------------------------------
__global__ __launch_bounds__(256) void vtrans(const u16* __restrict__ QKV,
                                              u16* __restrict__ Vt) {
    int idx = blockIdx.x * 256 + threadIdx.x;  // 0 .. M_*KV_-1
    int t    = idx & (T_ - 1);
    int rest = idx >> 11;
    int d    = rest & 63;
    int gb   = rest >> 6;
    int b    = gb >> 2, g = gb & 3;
    Vt[idx] = QKV[(size_t)(b * T_ + t) * QS_ + D_ + KV_ + g * 64 + d];
}

// ---------------------------------------------------------------------------
// Flash attention (causal), bound-exploiting softmax (|s|<=8 after rms-norm,
// so exp never overflows: no running max, no rescale).
// Block = 4 waves, wave w owns q-rows tqb*64 + w*16 .. +15 for one (b,h).
// 64-key tiles: S 16x64 (8 MFMA), P via per-wave LDS (C->A layout), PV 8 MFMA.
// No __syncthreads in the loop (per-wave private LDS).
// ---------------------------------------------------------------------------
__global__ __launch_bounds__(256) void flash(const u16* __restrict__ QKV,
                                             const u16* __restrict__ Vt,
                                             u16* __restrict__ Y) {
    const int tqb = blockIdx.x;     // 0..T_/64-1
    const int h   = blockIdx.y;
    const int b   = blockIdx.z;
    const int g   = h >> 2;
    const int w    = threadIdx.x >> 6;
    const int lane = threadIdx.x & 63;
    const int quad = lane >> 4, l16 = lane & 15;
    const int m = tqb * 64 + w * 16;   // first q row of this wave

    __shared__ u16 P[4][16][72];       // per-wave P tile, +8 pad (stride 144B)

    const u16* qp = QKV + (size_t)(b * T_ + m + l16) * QS_ + h * HD_ + quad * 8;
    short8 aq0 = *(const short8*)(qp);
    short8 aq1 = *(const short8*)(qp + 32);

    floatx4 acc[4];
#pragma unroll
    for (int i = 0; i < 4; i++) acc[i] = (floatx4){0.f, 0.f, 0.f, 0.f};
    float lrow[4] = {0.f, 0.f, 0.f, 0.f};

    const u16* kp = QKV + (size_t)(b * T_ + l16) * QS_ + D_ + g * HD_ + quad * 8;
    const u16* vp = Vt + (size_t)((b * 4 + g) * HD_ + l16) * T_ + quad * 8;

    const int ntiles = (m + 79) >> 6;  // tiles covering keys 0..m+15
    for (int tk = 0; tk < ntiles; tk++) {
        // K fragments: 4 nt x 2 kk
        const u16* kt = kp + (size_t)(tk * 64) * QS_;
        short8 bk[4][2];
#pragma unroll
        for (int nt = 0; nt < 4; nt++) {
            const u16* kr = kt + (size_t)(nt * 16) * QS_;
            bk[nt][0] = *(const short8*)(kr);
            bk[nt][1] = *(const short8*)(kr + 32);
        }
        floatx4 S[4];
#pragma unroll
        for (int nt = 0; nt < 4; nt++) {
            S[nt] = (floatx4){0.f, 0.f, 0.f, 0.f};
            S[nt] = __builtin_amdgcn_mfma_f32_16x16x32_bf16(aq0, bk[nt][0], S[nt], 0, 0, 0);
            S[nt] = __builtin_amdgcn_mfma_f32_16x16x32_bf16(aq1, bk[nt][1], S[nt], 0, 0, 0);
        }
        // softmax (no max-tracking): mask, exp, row-sum
#pragma unroll
        for (int r = 0; r < 4; r++) {
            int row = m + quad * 4 + r;
            float ps = 0.f;
#pragma unroll
            for (int nt = 0; nt < 4; nt++) {
                int key = tk * 64 + nt * 16 + l16;
                float p = (key <= row) ? __expf(S[nt][r]) : 0.f;
                ps += p;
                P[w][quad * 4 + r][nt * 16 + l16] = f2b(p);
            }
#pragma unroll
            for (int off = 1; off < 16; off <<= 1) ps += __shfl_xor(ps, off);
            lrow[r] += ps;
        }
        // P fragments (A-layout) + V fragments, PV MFMAs
        short8 pf0 = *(const short8*)&P[w][l16][quad * 8];
        short8 pf1 = *(const short8*)&P[w][l16][quad * 8 + 32];
        const u16* vt2 = vp + tk * 64;
#pragma unroll
        for (int dd = 0; dd < 4; dd++) {
            const u16* vr = vt2 + (size_t)(dd * 16) * T_;
            short8 bv0 = *(const short8*)(vr);
            short8 bv1 = *(const short8*)(vr + 32);
            acc[dd] = __builtin_amdgcn_mfma_f32_16x16x32_bf16(pf0, bv0, acc[dd], 0, 0, 0);
            acc[dd] = __builtin_amdgcn_mfma_f32_16x16x32_bf16(pf1, bv1, acc[dd], 0, 0, 0);
        }
    }

#pragma unroll
    for (int r = 0; r < 4; r++) {
        float invl = 1.0f / lrow[r];
        int row = m + quad * 4 + r;
        u16* yp = Y + (size_t)(b * T_ + row) * D_ + h * HD_ + l16;
#pragma unroll
        for (int dd = 0; dd < 4; dd++)
            yp[dd * 16] = f2b(acc[dd][r] * invl);
    }
}

// ---------------------------------------------------------------------------
extern "C" void kernel_launch(void* const* d_in, const int* in_sizes, int n_in,
                              void* d_out, int out_size, void* d_ws, size_t ws_size,
                              hipStream_t stream) {
    const float* x    = (const float*)d_in[0];
    const float* Wq   = (const float*)d_in[1];
    const float* Wk   = (const float*)d_in[2];
    const float* Wv   = (const float*)d_in[3];
    const float* Wp   = (const float*)d_in[4];
    const float* gain = (const float*)d_in[5];
    float* out = (float*)d_out;

    u16* xb   = (u16*)d_ws;                    // 4M elems
    u16* Wcat = xb   + (size_t)M_ * D_;        // 1.5M  (Wq;Wk;Wv rows, K=1024)
    u16* Wpb  = Wcat + (size_t)QS_ * D_;       // 1M
    u16* QKV  = Wpb  + (size_t)D_ * D_;        // 6M   (4096 x 1536)
    u16* Vt   = QKV  + (size_t)M_ * QS_;       // 1M
    u16* Y    = Vt   + (size_t)M_ * KV_;       // 4M   (~35 MB total)

    castk<<<(M_ * D_) / 1024, 256, 0, stream>>>(x,  xb,  M_ * D_);
    castk<<<(D_ * D_) / 1024, 256, 0, stream>>>(Wq, Wcat, D_ * D_);
    castk<<<(KV_ * D_) / 1024, 256, 0, stream>>>(Wk, Wcat + (size_t)D_ * D_, KV_ * D_);
    castk<<<(KV_ * D_) / 1024, 256, 0, stream>>>(Wv, Wcat + (size_t)(D_ + KV_) * D_, KV_ * D_);
    castk<<<(D_ * D_) / 1024, 256, 0, stream>>>(Wp, Wpb, D_ * D_);

    // fused QKV projection: [4096 x 1536] = xb[4096x1024] * Wcat[1536x1024]^T
    gemm128<u16><<<dim3(QS_ / 128, M_ / 128), 256, 0, stream>>>(xb, Wcat, QKV,
                                                                M_, QS_, D_, QS_);

    norm_rope<<<(M_ * H_ + M_ * HKV_) / 4, 256, 0, stream>>>(QKV, gain);
    vtrans<<<(M_ * KV_) / 256, 256, 0, stream>>>(QKV, Vt);

    flash<<<dim3(T_ / 64, H_, B_), 256, 0, stream>>>(QKV, Vt, Y);

    gemm128<float><<<dim3(D_ / 128, M_ / 128), 256, 0, stream>>>(Y, Wpb, out,
                                                                 M_, D_, D_, D_);
}

// Round 4
// 285.515 us; speedup vs baseline: 1.9353x; 1.3900x over previous
//
#include <hip/hip_runtime.h>
#include <cstdint>
#include <cstddef>

typedef __attribute__((ext_vector_type(8))) short short8;
typedef __attribute__((ext_vector_type(4))) float floatx4;
typedef __attribute__((ext_vector_type(4))) short short4v;
typedef unsigned short u16;

#define B_   2
#define T_   2048
#define D_   1024
#define H_   16
#define HKV_ 4
#define HD_  64
#define KV_  256
#define M_   4096   // B*T
#define QS_  1536   // fused QKV row stride (1024 Q + 256 K + 256 V)

__device__ __forceinline__ float b2f(u16 u) {
    union { unsigned int i; float f; } v; v.i = ((unsigned int)u) << 16; return v.f;
}
__device__ __forceinline__ u16 f2b(float f) {
    union { float f; unsigned int i; } v; v.f = f;
    unsigned int r = v.i + 0x7FFF + ((v.i >> 16) & 1);
    return (u16)(r >> 16);
}

// async global->LDS, 16 bytes per lane (global_load_lds_dwordx4)
__device__ __forceinline__ void async16(const u16* g, u16* l) {
    __builtin_amdgcn_global_load_lds(
        (const __attribute__((address_space(1))) unsigned int*)g,
        (__attribute__((address_space(3))) unsigned int*)l, 16, 0, 0);
}

// ---------------------------------------------------------------------------
// fp32 -> bf16 (RNE) cast, 4 elements/thread.
// ---------------------------------------------------------------------------
__global__ __launch_bounds__(256) void castk(const float* __restrict__ in,
                                             u16* __restrict__ out, int n) {
    int i = (blockIdx.x * 256 + threadIdx.x) * 4;
    if (i >= n) return;
    float4 v = *(const float4*)(in + i);
    short4v o;
    o.x = (short)f2b(v.x); o.y = (short)f2b(v.y);
    o.z = (short)f2b(v.z); o.w = (short)f2b(v.w);
    *(short4v*)(out + i) = o;
}

// ---------------------------------------------------------------------------
// m97-style GEMM: C[M,N] = A[M,K] * W[N,K]^T  (bf16 in, fp32 acc, OutT out)
// 128x128 tile, BK=32, 4 waves, global_load_lds width=16, 2-barrier K-loop.
// ---------------------------------------------------------------------------
template <typename OutT>
__global__ __launch_bounds__(256) void gemm128(const u16* __restrict__ A,
                                               const u16* __restrict__ W,
                                               OutT* __restrict__ C,
                                               int M, int N, int K, int ldc) {
    __shared__ u16 As[128 * 32];
    __shared__ u16 Bs[128 * 32];
    const int t = threadIdx.x;
    const int wave = t >> 6, lane = t & 63;
    const int quad = lane >> 4, l16 = lane & 15;
    const int wm = (wave >> 1) * 64, wn = (wave & 1) * 64;
    const int m0 = blockIdx.y * 128, n0 = blockIdx.x * 128;

    floatx4 acc[4][4];
#pragma unroll
    for (int i = 0; i < 4; i++)
#pragma unroll
        for (int j = 0; j < 4; j++) acc[i][j] = (floatx4){0.f, 0.f, 0.f, 0.f};

    const int sr = t >> 2, sc = (t & 3) * 8;
    const u16* ga = A + (size_t)(m0 + sr) * K + sc;
    const u16* gb = W + (size_t)(n0 + sr) * K + sc;
    u16* lA = As + t * 8;
    u16* lB = Bs + t * 8;

    async16(ga, lA);
    async16(ga + (size_t)64 * K, lA + 64 * 32);
    async16(gb, lB);
    async16(gb + (size_t)64 * K, lB + 64 * 32);

    for (int kt = 0; kt < K; kt += 32) {
        __syncthreads();
        short8 af[4], bf[4];
#pragma unroll
        for (int mt = 0; mt < 4; mt++)
            af[mt] = *(const short8*)(As + (wm + mt * 16 + l16) * 32 + quad * 8);
#pragma unroll
        for (int nt = 0; nt < 4; nt++)
            bf[nt] = *(const short8*)(Bs + (wn + nt * 16 + l16) * 32 + quad * 8);
#pragma unroll
        for (int mt = 0; mt < 4; mt++)
#pragma unroll
            for (int nt = 0; nt < 4; nt++)
                acc[mt][nt] = __builtin_amdgcn_mfma_f32_16x16x32_bf16(
                    af[mt], bf[nt], acc[mt][nt], 0, 0, 0);
        __syncthreads();
        if (kt + 32 < K) {
            const u16* ga2 = ga + kt + 32;
            const u16* gb2 = gb + kt + 32;
            async16(ga2, lA);
            async16(ga2 + (size_t)64 * K, lA + 64 * 32);
            async16(gb2, lB);
            async16(gb2 + (size_t)64 * K, lB + 64 * 32);
        }
    }

#pragma unroll
    for (int mt = 0; mt < 4; mt++)
#pragma unroll
        for (int nt = 0; nt < 4; nt++)
#pragma unroll
            for (int r = 0; r < 4; r++) {
                int row = m0 + wm + mt * 16 + quad * 4 + r;
                int col = n0 + wn + nt * 16 + l16;
                float val = acc[mt][nt][r];
                if constexpr (sizeof(OutT) == 4) C[(size_t)row * ldc + col] = val;
                else                             C[(size_t)row * ldc + col] = (OutT)f2b(val);
            }
}

// ---------------------------------------------------------------------------
// Fused per-head RMSNorm + RoPE (+ q_gain and 1/sqrt(hd) folded into Q).
// ---------------------------------------------------------------------------
__global__ __launch_bounds__(256) void norm_rope(u16* __restrict__ QKV,
                                                 const float* __restrict__ gain) {
    const int task = blockIdx.x * 4 + (threadIdx.x >> 6);
    const int lane = threadIdx.x & 63;

    u16* ptr; float gs; int t;
    if (task < M_ * H_) {
        int row = task >> 4, h = task & 15;
        ptr = QKV + (size_t)row * QS_ + h * HD_;
        gs  = gain[h] * 0.125f;
        t   = row & (T_ - 1);
    } else {
        int k = task - M_ * H_;
        int row = k >> 2, h = k & 3;
        ptr = QKV + (size_t)row * QS_ + D_ + h * HD_;
        gs  = 1.0f;
        t   = row & (T_ - 1);
    }

    float v = b2f(ptr[lane]);
    float ss = v * v;
#pragma unroll
    for (int off = 32; off; off >>= 1) ss += __shfl_xor(ss, off);
    float inv = rsqrtf(ss * (1.0f / 64.0f) + 1.1920929e-7f);
    v *= inv;

    const int i = lane & 31;
    float freq = powf(10000.0f, -(float)i * (1.0f / 32.0f));
    float ang  = (float)t * freq;
    float c = cosf(ang), s = sinf(ang);
    float other = __shfl_xor(v, 32);
    float out = (lane < 32) ? (v * c + other * s) : (v * c - other * s);
    ptr[lane] = f2b(out * gs);
}

// ---------------------------------------------------------------------------
// V transpose from fused QKV.
// ---------------------------------------------------------------------------
__global__ __launch_bounds__(256) void vtrans(const u16* __restrict__ QKV,
                                              u16* __restrict__ Vt) {
    int idx = blockIdx.x * 256 + threadIdx.x;
    int t    = idx & (T_ - 1);
    int rest = idx >> 11;
    int d    = rest & 63;
    int gb   = rest >> 6;
    int b    = gb >> 2, g = gb & 3;
    Vt[idx] = QKV[(size_t)(b * T_ + t) * QS_ + D_ + KV_ + g * 64 + d];
}

// ---------------------------------------------------------------------------
// Flash attention (causal), no-max softmax (|s|<=8 post-RMSNorm).
// Block handles the COMPLEMENTARY q-tile pair (xp, 31-xp): uniform 33
// tile-units per wave -> perfect CU balance. Wave w owns rows tq*64+w*16..+15
// of both strips. Row-sum l via all-ones MFMA (no shuffle reduces).
// K tile register-prefetched; V loaded at iter start, used at iter end.
// ---------------------------------------------------------------------------
__global__ __launch_bounds__(256, 2) void flash(const u16* __restrict__ QKV,
                                                const u16* __restrict__ Vt,
                                                u16* __restrict__ Y) {
    const int xp = blockIdx.x;      // 0..15
    const int h  = blockIdx.y;
    const int b  = blockIdx.z;
    const int g  = h >> 2;
    const int w    = threadIdx.x >> 6;
    const int lane = threadIdx.x & 63;
    const int quad = lane >> 4, l16 = lane & 15;

    const int mA = xp * 64 + w * 16;          // early strip
    const int mB = (31 - xp) * 64 + w * 16;   // late strip
    const int nA = xp + 1;                    // k-tiles for strip A
    const int nB = 32 - xp;                   // k-tiles for strip B

    __shared__ __align__(16) u16 P[4][2][16][72];   // per-wave, per-strip

    const u16* qpA = QKV + (size_t)(b * T_ + mA + l16) * QS_ + h * HD_ + quad * 8;
    const u16* qpB = QKV + (size_t)(b * T_ + mB + l16) * QS_ + h * HD_ + quad * 8;
    short8 aqA0 = *(const short8*)(qpA);
    short8 aqA1 = *(const short8*)(qpA + 32);
    short8 aqB0 = *(const short8*)(qpB);
    short8 aqB1 = *(const short8*)(qpB + 32);

    short8 ones;
#pragma unroll
    for (int i = 0; i < 8; i++) ones[i] = (short)0x3F80;  // bf16 1.0

    floatx4 accA[4], accB[4];
#pragma unroll
    for (int i = 0; i < 4; i++) {
        accA[i] = (floatx4){0.f, 0.f, 0.f, 0.f};
        accB[i] = (floatx4){0.f, 0.f, 0.f, 0.f};
    }
    floatx4 lAcc = (floatx4){0.f, 0.f, 0.f, 0.f};
    floatx4 lBcc = (floatx4){0.f, 0.f, 0.f, 0.f};

    const u16* kp = QKV + (size_t)(b * T_ + l16) * QS_ + D_ + g * HD_ + quad * 8;
    const u16* vp = Vt + (size_t)((b * 4 + g) * HD_ + l16) * T_ + quad * 8;

    short8 kc[4][2], kn[4][2];
#pragma unroll
    for (int nt = 0; nt < 4; nt++) {
        const u16* kr = kp + (size_t)(nt * 16) * QS_;
        kc[nt][0] = *(const short8*)(kr);
        kc[nt][1] = *(const short8*)(kr + 32);
    }

    for (int tk = 0; tk < nB; tk++) {
        const bool dual = (tk < nA);
        // prefetch next K tile
        if (tk + 1 < nB) {
            const u16* kt = kp + (size_t)((tk + 1) * 64) * QS_;
#pragma unroll
            for (int nt = 0; nt < 4; nt++) {
                const u16* kr = kt + (size_t)(nt * 16) * QS_;
                kn[nt][0] = *(const short8*)(kr);
                kn[nt][1] = *(const short8*)(kr + 32);
            }
        }
        // V fragments for this tile (consumed at iteration end)
        short8 vf[4][2];
        {
            const u16* vt2 = vp + tk * 64;
#pragma unroll
            for (int dd = 0; dd < 4; dd++) {
                const u16* vr = vt2 + (size_t)(dd * 16) * T_;
                vf[dd][0] = *(const short8*)(vr);
                vf[dd][1] = *(const short8*)(vr + 32);
            }
        }

        // S = Q K^T for strip B (always) and strip A (while dual)
        floatx4 SB[4], SA[4];
#pragma unroll
        for (int nt = 0; nt < 4; nt++) {
            SB[nt] = (floatx4){0.f, 0.f, 0.f, 0.f};
            SB[nt] = __builtin_amdgcn_mfma_f32_16x16x32_bf16(aqB0, kc[nt][0], SB[nt], 0, 0, 0);
            SB[nt] = __builtin_amdgcn_mfma_f32_16x16x32_bf16(aqB1, kc[nt][1], SB[nt], 0, 0, 0);
        }
        if (dual) {
#pragma unroll
            for (int nt = 0; nt < 4; nt++) {
                SA[nt] = (floatx4){0.f, 0.f, 0.f, 0.f};
                SA[nt] = __builtin_amdgcn_mfma_f32_16x16x32_bf16(aqA0, kc[nt][0], SA[nt], 0, 0, 0);
                SA[nt] = __builtin_amdgcn_mfma_f32_16x16x32_bf16(aqA1, kc[nt][1], SA[nt], 0, 0, 0);
            }
        }

        // exp + mask + store P  (mask only on each strip's last tile)
        const bool maskB = (tk == nB - 1);
#pragma unroll
        for (int r = 0; r < 4; r++) {
#pragma unroll
            for (int nt = 0; nt < 4; nt++) {
                float p = __expf(SB[nt][r]);
                if (maskB) {
                    int key = tk * 64 + nt * 16 + l16;
                    int row = mB + quad * 4 + r;
                    p = (key <= row) ? p : 0.f;
                }
                P[w][1][quad * 4 + r][nt * 16 + l16] = f2b(p);
            }
        }
        if (dual) {
            const bool maskA = (tk == nA - 1);
#pragma unroll
            for (int r = 0; r < 4; r++) {
#pragma unroll
                for (int nt = 0; nt < 4; nt++) {
                    float p = __expf(SA[nt][r]);
                    if (maskA) {
                        int key = tk * 64 + nt * 16 + l16;
                        int row = mA + quad * 4 + r;
                        p = (key <= row) ? p : 0.f;
                    }
                    P[w][0][quad * 4 + r][nt * 16 + l16] = f2b(p);
                }
            }
        }

        // P (A-layout) reads; PV and row-sum MFMAs
        short8 pfB0 = *(const short8*)&P[w][1][l16][quad * 8];
        short8 pfB1 = *(const short8*)&P[w][1][l16][quad * 8 + 32];
#pragma unroll
        for (int dd = 0; dd < 4; dd++) {
            accB[dd] = __builtin_amdgcn_mfma_f32_16x16x32_bf16(pfB0, vf[dd][0], accB[dd], 0, 0, 0);
            accB[dd] = __builtin_amdgcn_mfma_f32_16x16x32_bf16(pfB1, vf[dd][1], accB[dd], 0, 0, 0);
        }
        lBcc = __builtin_amdgcn_mfma_f32_16x16x32_bf16(pfB0, ones, lBcc, 0, 0, 0);
        lBcc = __builtin_amdgcn_mfma_f32_16x16x32_bf16(pfB1, ones, lBcc, 0, 0, 0);
        if (dual) {
            short8 pfA0 = *(const short8*)&P[w][0][l16][quad * 8];
            short8 pfA1 = *(const short8*)&P[w][0][l16][quad * 8 + 32];
#pragma unroll
            for (int dd = 0; dd < 4; dd++) {
                accA[dd] = __builtin_amdgcn_mfma_f32_16x16x32_bf16(pfA0, vf[dd][0], accA[dd], 0, 0, 0);
                accA[dd] = __builtin_amdgcn_mfma_f32_16x16x32_bf16(pfA1, vf[dd][1], accA[dd], 0, 0, 0);
            }
            lAcc = __builtin_amdgcn_mfma_f32_16x16x32_bf16(pfA0, ones, lAcc, 0, 0, 0);
            lAcc = __builtin_amdgcn_mfma_f32_16x16x32_bf16(pfA1, ones, lAcc, 0, 0, 0);
        }

        // rotate prefetched K
#pragma unroll
        for (int nt = 0; nt < 4; nt++) {
            kc[nt][0] = kn[nt][0];
            kc[nt][1] = kn[nt][1];
        }
    }

    // epilogue: O = acc / l
#pragma unroll
    for (int r = 0; r < 4; r++) {
        float invA = 1.0f / lAcc[r];
        float invB = 1.0f / lBcc[r];
        int rowA = mA + quad * 4 + r;
        int rowB = mB + quad * 4 + r;
        u16* ypA = Y + (size_t)(b * T_ + rowA) * D_ + h * HD_ + l16;
        u16* ypB = Y + (size_t)(b * T_ + rowB) * D_ + h * HD_ + l16;
#pragma unroll
        for (int dd = 0; dd < 4; dd++) {
            ypA[dd * 16] = f2b(accA[dd][r] * invA);
            ypB[dd * 16] = f2b(accB[dd][r] * invB);
        }
    }
}

// ---------------------------------------------------------------------------
extern "C" void kernel_launch(void* const* d_in, const int* in_sizes, int n_in,
                              void* d_out, int out_size, void* d_ws, size_t ws_size,
                              hipStream_t stream) {
    const float* x    = (const float*)d_in[0];
    const float* Wq   = (const float*)d_in[1];
    const float* Wk   = (const float*)d_in[2];
    const float* Wv   = (const float*)d_in[3];
    const float* Wp   = (const float*)d_in[4];
    const float* gain = (const float*)d_in[5];
    float* out = (float*)d_out;

    u16* xb   = (u16*)d_ws;
    u16* Wcat = xb   + (size_t)M_ * D_;
    u16* Wpb  = Wcat + (size_t)QS_ * D_;
    u16* QKV  = Wpb  + (size_t)D_ * D_;
    u16* Vt   = QKV  + (size_t)M_ * QS_;
    u16* Y    = Vt   + (size_t)M_ * KV_;

    castk<<<(M_ * D_) / 1024, 256, 0, stream>>>(x,  xb,  M_ * D_);
    castk<<<(D_ * D_) / 1024, 256, 0, stream>>>(Wq, Wcat, D_ * D_);
    castk<<<(KV_ * D_) / 1024, 256, 0, stream>>>(Wk, Wcat + (size_t)D_ * D_, KV_ * D_);
    castk<<<(KV_ * D_) / 1024, 256, 0, stream>>>(Wv, Wcat + (size_t)(D_ + KV_) * D_, KV_ * D_);
    castk<<<(D_ * D_) / 1024, 256, 0, stream>>>(Wp, Wpb, D_ * D_);

    gemm128<u16><<<dim3(QS_ / 128, M_ / 128), 256, 0, stream>>>(xb, Wcat, QKV,
                                                                M_, QS_, D_, QS_);

    norm_rope<<<(M_ * H_ + M_ * HKV_) / 4, 256, 0, stream>>>(QKV, gain);
    vtrans<<<(M_ * KV_) / 256, 256, 0, stream>>>(QKV, Vt);

    flash<<<dim3(16, H_, B_), 256, 0, stream>>>(QKV, Vt, Y);

    gemm128<float><<<dim3(D_ / 128, M_ / 128), 256, 0, stream>>>(Y, Wpb, out,
                                                                 M_, D_, D_, D_);
}

// Round 5
// 208.809 us; speedup vs baseline: 2.6463x; 1.3673x over previous
//
#include <hip/hip_runtime.h>
#include <cstdint>
#include <cstddef>

typedef __attribute__((ext_vector_type(8))) short short8;
typedef __attribute__((ext_vector_type(4))) float floatx4;
typedef __attribute__((ext_vector_type(4))) short short4v;
typedef unsigned short u16;
typedef unsigned int u32;

#define B_   2
#define T_   2048
#define D_   1024
#define H_   16
#define HKV_ 4
#define HD_  64
#define KV_  256
#define M_   4096   // B*T
#define QS_  1536   // fused QKV row stride (1024 Q + 256 K + 256 V)

__device__ __forceinline__ float b2f(u16 u) {
    union { u32 i; float f; } v; v.i = ((u32)u) << 16; return v.f;
}
__device__ __forceinline__ u16 f2b(float f) {
    union { float f; u32 i; } v; v.f = f;
    u32 r = v.i + 0x7FFF + ((v.i >> 16) & 1);
    return (u16)(r >> 16);
}
// pack hi16(a), hi16(b) -> one u32 (truncation-rounded bf16 pair)
__device__ __forceinline__ u32 pack_hi(float a, float b) {
    union { float f; u32 u; } ua, ub; ua.f = a; ub.f = b;
    return (ua.u >> 16) | (ub.u & 0xFFFF0000u);
}

// async global->LDS, 16 bytes per lane (global_load_lds_dwordx4)
__device__ __forceinline__ void async16(const u16* g, u16* l) {
    __builtin_amdgcn_global_load_lds(
        (const __attribute__((address_space(1))) u32*)g,
        (__attribute__((address_space(3))) u32*)l, 16, 0, 0);
}

// ---------------------------------------------------------------------------
// fp32 -> bf16 (RNE) cast, 4 elements/thread.
// ---------------------------------------------------------------------------
__global__ __launch_bounds__(256) void castk(const float* __restrict__ in,
                                             u16* __restrict__ out, int n) {
    int i = (blockIdx.x * 256 + threadIdx.x) * 4;
    if (i >= n) return;
    float4 v = *(const float4*)(in + i);
    short4v o;
    o.x = (short)f2b(v.x); o.y = (short)f2b(v.y);
    o.z = (short)f2b(v.z); o.w = (short)f2b(v.w);
    *(short4v*)(out + i) = o;
}

// ---------------------------------------------------------------------------
// RoPE cos/sin table: tab[t*32+i] = (cos(t*f_i), sin(t*f_i))
// ---------------------------------------------------------------------------
__global__ __launch_bounds__(256) void ropetab(float2* __restrict__ tab) {
    int idx = blockIdx.x * 256 + threadIdx.x;   // 0..65535
    int t = idx >> 5, i = idx & 31;
    float freq = exp2f(-(float)i * (13.287712379549449f / 32.0f)); // 10000^(-i/32)
    float ang = (float)t * freq;
    tab[idx] = make_float2(cosf(ang), sinf(ang));
}

// ---------------------------------------------------------------------------
// m97-style GEMM: C[M,N] = A[M,K] * W[N,K]^T  (bf16 in, fp32 acc, OutT out)
// ---------------------------------------------------------------------------
template <typename OutT>
__global__ __launch_bounds__(256) void gemm128(const u16* __restrict__ A,
                                               const u16* __restrict__ W,
                                               OutT* __restrict__ C,
                                               int M, int N, int K, int ldc) {
    __shared__ u16 As[128 * 32];
    __shared__ u16 Bs[128 * 32];
    const int t = threadIdx.x;
    const int wave = t >> 6, lane = t & 63;
    const int quad = lane >> 4, l16 = lane & 15;
    const int wm = (wave >> 1) * 64, wn = (wave & 1) * 64;
    const int m0 = blockIdx.y * 128, n0 = blockIdx.x * 128;

    floatx4 acc[4][4];
#pragma unroll
    for (int i = 0; i < 4; i++)
#pragma unroll
        for (int j = 0; j < 4; j++) acc[i][j] = (floatx4){0.f, 0.f, 0.f, 0.f};

    const int sr = t >> 2, sc = (t & 3) * 8;
    const u16* ga = A + (size_t)(m0 + sr) * K + sc;
    const u16* gb = W + (size_t)(n0 + sr) * K + sc;
    u16* lA = As + t * 8;
    u16* lB = Bs + t * 8;

    async16(ga, lA);
    async16(ga + (size_t)64 * K, lA + 64 * 32);
    async16(gb, lB);
    async16(gb + (size_t)64 * K, lB + 64 * 32);

    for (int kt = 0; kt < K; kt += 32) {
        __syncthreads();
        short8 af[4], bf[4];
#pragma unroll
        for (int mt = 0; mt < 4; mt++)
            af[mt] = *(const short8*)(As + (wm + mt * 16 + l16) * 32 + quad * 8);
#pragma unroll
        for (int nt = 0; nt < 4; nt++)
            bf[nt] = *(const short8*)(Bs + (wn + nt * 16 + l16) * 32 + quad * 8);
#pragma unroll
        for (int mt = 0; mt < 4; mt++)
#pragma unroll
            for (int nt = 0; nt < 4; nt++)
                acc[mt][nt] = __builtin_amdgcn_mfma_f32_16x16x32_bf16(
                    af[mt], bf[nt], acc[mt][nt], 0, 0, 0);
        __syncthreads();
        if (kt + 32 < K) {
            const u16* ga2 = ga + kt + 32;
            const u16* gb2 = gb + kt + 32;
            async16(ga2, lA);
            async16(ga2 + (size_t)64 * K, lA + 64 * 32);
            async16(gb2, lB);
            async16(gb2 + (size_t)64 * K, lB + 64 * 32);
        }
    }

#pragma unroll
    for (int mt = 0; mt < 4; mt++)
#pragma unroll
        for (int nt = 0; nt < 4; nt++)
#pragma unroll
            for (int r = 0; r < 4; r++) {
                int row = m0 + wm + mt * 16 + quad * 4 + r;
                int col = n0 + wn + nt * 16 + l16;
                float val = acc[mt][nt][r];
                if constexpr (sizeof(OutT) == 4) C[(size_t)row * ldc + col] = val;
                else                             C[(size_t)row * ldc + col] = (OutT)f2b(val);
            }
}

// ---------------------------------------------------------------------------
// Fused per-head RMSNorm + RoPE. Q gets gain/8 * log2(e) folded in (flash
// then uses exp2). K gets gs=1. cos/sin from table.
// ---------------------------------------------------------------------------
__global__ __launch_bounds__(256) void norm_rope(u16* __restrict__ QKV,
                                                 const float* __restrict__ gain,
                                                 const float2* __restrict__ tab) {
    const int task = blockIdx.x * 4 + (threadIdx.x >> 6);
    const int lane = threadIdx.x & 63;

    u16* ptr; float gs; int t;
    if (task < M_ * H_) {
        int row = task >> 4, h = task & 15;
        ptr = QKV + (size_t)row * QS_ + h * HD_;
        gs  = gain[h] * 0.125f * 1.4426950408889634f;  // gain/sqrt(64)*log2(e)
        t   = row & (T_ - 1);
    } else {
        int k = task - M_ * H_;
        int row = k >> 2, h = k & 3;
        ptr = QKV + (size_t)row * QS_ + D_ + h * HD_;
        gs  = 1.0f;
        t   = row & (T_ - 1);
    }

    float v = b2f(ptr[lane]);
    float ss = v * v;
#pragma unroll
    for (int off = 32; off; off >>= 1) ss += __shfl_xor(ss, off);
    float inv = rsqrtf(ss * (1.0f / 64.0f) + 1.1920929e-7f);
    v *= inv;

    float2 cs = tab[t * 32 + (lane & 31)];
    float other = __shfl_xor(v, 32);
    float out = (lane < 32) ? (v * cs.x + other * cs.y) : (v * cs.x - other * cs.y);
    ptr[lane] = f2b(out * gs);
}

// ---------------------------------------------------------------------------
// V transpose: coalesced 16B reads, scattered 2B writes.
// ---------------------------------------------------------------------------
__global__ __launch_bounds__(256) void vtrans(const u16* __restrict__ QKV,
                                              u16* __restrict__ Vt) {
    int u = blockIdx.x * 256 + threadIdx.x;    // 0 .. 131071
    int db = u & 7, g = (u >> 3) & 3, t = (u >> 5) & (T_ - 1), b = u >> 16;
    short8 v = *(const short8*)(QKV + (size_t)(b * T_ + t) * QS_ + D_ + KV_ + g * 64 + db * 8);
#pragma unroll
    for (int j = 0; j < 8; j++)
        Vt[(size_t)((b * 4 + g) * 64 + db * 8 + j) * T_ + t] = (u16)v[j];
}

// ---------------------------------------------------------------------------
// Flash attention (causal), no-max softmax via exp2 (log2e pre-folded into Q).
// Complementary q-tile pair (xp, 31-xp) per block: uniform 33 tile-units.
// K/V tiles staged into LDS via global_load_lds (XOR-swizzled chunks);
// S^T computed (A=K, B=Q) so P-writes are packed ds_write_b64;
// P LDS layout identical to verified round-4 code; l via all-ones MFMA.
// ---------------------------------------------------------------------------
__global__ __launch_bounds__(256) void flash(const u16* __restrict__ QKV,
                                             const u16* __restrict__ Vtr,
                                             u16* __restrict__ Y) {
    const int xp = blockIdx.x;      // 0..15
    const int h  = blockIdx.y;
    const int b  = blockIdx.z;
    const int g  = h >> 2;
    const int w    = threadIdx.x >> 6;
    const int lane = threadIdx.x & 63;
    const int quad = lane >> 4, l16 = lane & 15;

    __shared__ u16 Kt[64 * 64];
    __shared__ u16 Vs[64 * 64];
    __shared__ __align__(16) u16 P[4][2][16][72];

    const int mA = xp * 64 + w * 16;
    const int mB = (31 - xp) * 64 + w * 16;
    const int nA = xp + 1;
    const int nB = 32 - xp;

    // Q fragments
    const u16* qpA = QKV + (size_t)(b * T_ + mA + l16) * QS_ + h * HD_ + quad * 8;
    const u16* qpB = QKV + (size_t)(b * T_ + mB + l16) * QS_ + h * HD_ + quad * 8;
    short8 aqA0 = *(const short8*)(qpA);
    short8 aqA1 = *(const short8*)(qpA + 32);
    short8 aqB0 = *(const short8*)(qpB);
    short8 aqB1 = *(const short8*)(qpB + 32);

    short8 ones;
#pragma unroll
    for (int i = 0; i < 8; i++) ones[i] = (short)0x3F80;  // bf16 1.0

    floatx4 accA[4], accB[4];
#pragma unroll
    for (int i = 0; i < 4; i++) {
        accA[i] = (floatx4){0.f, 0.f, 0.f, 0.f};
        accB[i] = (floatx4){0.f, 0.f, 0.f, 0.f};
    }
    floatx4 lAcc = (floatx4){0.f, 0.f, 0.f, 0.f};
    floatx4 lBcc = (floatx4){0.f, 0.f, 0.f, 0.f};

    // staging pointers: wave w stages rows w*16..w*16+15 of each 64-row tile
    const int srow = w * 16 + (lane >> 3);
    const int sseg = (lane & 7) ^ ((lane >> 3) & 7);   // XOR swizzle
    const u16* kg = QKV + (size_t)(b * T_ + srow) * QS_ + D_ + g * 64 + sseg * 8;
    const u16* vg = Vtr + (size_t)((b * 4 + g) * 64 + srow) * T_ + sseg * 8;
    u16* klds = Kt + w * 1024 + lane * 8;
    u16* vlds = Vs + w * 1024 + lane * 8;

    // swizzled frag read offsets (u16 units)
    const int sw0 = (quad ^ (l16 & 7)) * 8;
    const int sw1 = ((4 + quad) ^ (l16 & 7)) * 8;

    // stage tile 0
    async16(kg, klds);
    async16(kg + (size_t)8 * QS_, klds + 512);
    async16(vg, vlds);
    async16(vg + (size_t)8 * T_, vlds + 512);

    for (int tk = 0; tk < nB; tk++) {
        const bool dual = (tk < nA);
        __syncthreads();                          // staging of tile tk complete

        // --- K fragments + S^T MFMAs (D[m=key][n=q]) ---
        floatx4 SB[4], SA[4];
#pragma unroll
        for (int nt = 0; nt < 4; nt++) {
            const u16* kr = Kt + (nt * 16 + l16) * 64;
            short8 kf0 = *(const short8*)(kr + sw0);
            short8 kf1 = *(const short8*)(kr + sw1);
            SB[nt] = (floatx4){0.f, 0.f, 0.f, 0.f};
            SB[nt] = __builtin_amdgcn_mfma_f32_16x16x32_bf16(kf0, aqB0, SB[nt], 0, 0, 0);
            SB[nt] = __builtin_amdgcn_mfma_f32_16x16x32_bf16(kf1, aqB1, SB[nt], 0, 0, 0);
            if (dual) {
                SA[nt] = (floatx4){0.f, 0.f, 0.f, 0.f};
                SA[nt] = __builtin_amdgcn_mfma_f32_16x16x32_bf16(kf0, aqA0, SA[nt], 0, 0, 0);
                SA[nt] = __builtin_amdgcn_mfma_f32_16x16x32_bf16(kf1, aqA1, SA[nt], 0, 0, 0);
            }
        }
        // --- V fragments (held in regs across the staging barrier) ---
        short8 vf[4][2];
#pragma unroll
        for (int dd = 0; dd < 4; dd++) {
            const u16* vr = Vs + (dd * 16 + l16) * 64;
            vf[dd][0] = *(const short8*)(vr + sw0);
            vf[dd][1] = *(const short8*)(vr + sw1);
        }
        __syncthreads();                          // all waves done reading K/V LDS
        if (tk + 1 < nB) {                        // DMA next tile during compute
            kg += (size_t)64 * QS_;
            vg += 64;
            async16(kg, klds);
            async16(kg + (size_t)8 * QS_, klds + 512);
            async16(vg, vlds);
            async16(vg + (size_t)8 * T_, vlds + 512);
        }

        // --- strip B: exp2, mask, packed P write ---
        const bool maskB = (tk == nB - 1);
        const int qB = mB + l16;
#pragma unroll
        for (int nt = 0; nt < 4; nt++) {
            float p[4];
#pragma unroll
            for (int r = 0; r < 4; r++) {
                float e = exp2f(SB[nt][r]);
                if (maskB) {
                    int key = tk * 64 + nt * 16 + quad * 4 + r;
                    e = (key <= qB) ? e : 0.f;
                }
                p[r] = e;
            }
            uint2 pw; pw.x = pack_hi(p[0], p[1]); pw.y = pack_hi(p[2], p[3]);
            *(uint2*)&P[w][1][l16][nt * 16 + quad * 4] = pw;
        }
        short8 pfB0 = *(const short8*)&P[w][1][l16][quad * 8];
        short8 pfB1 = *(const short8*)&P[w][1][l16][quad * 8 + 32];
#pragma unroll
        for (int dd = 0; dd < 4; dd++) {
            accB[dd] = __builtin_amdgcn_mfma_f32_16x16x32_bf16(pfB0, vf[dd][0], accB[dd], 0, 0, 0);
            accB[dd] = __builtin_amdgcn_mfma_f32_16x16x32_bf16(pfB1, vf[dd][1], accB[dd], 0, 0, 0);
        }
        lBcc = __builtin_amdgcn_mfma_f32_16x16x32_bf16(pfB0, ones, lBcc, 0, 0, 0);
        lBcc = __builtin_amdgcn_mfma_f32_16x16x32_bf16(pfB1, ones, lBcc, 0, 0, 0);

        // --- strip A (while dual) ---
        if (dual) {
            const bool maskA = (tk == nA - 1);
            const int qA = mA + l16;
#pragma unroll
            for (int nt = 0; nt < 4; nt++) {
                float p[4];
#pragma unroll
                for (int r = 0; r < 4; r++) {
                    float e = exp2f(SA[nt][r]);
                    if (maskA) {
                        int key = tk * 64 + nt * 16 + quad * 4 + r;
                        e = (key <= qA) ? e : 0.f;
                    }
                    p[r] = e;
                }
                uint2 pw; pw.x = pack_hi(p[0], p[1]); pw.y = pack_hi(p[2], p[3]);
                *(uint2*)&P[w][0][l16][nt * 16 + quad * 4] = pw;
            }
            short8 pfA0 = *(const short8*)&P[w][0][l16][quad * 8];
            short8 pfA1 = *(const short8*)&P[w][0][l16][quad * 8 + 32];
#pragma unroll
            for (int dd = 0; dd < 4; dd++) {
                accA[dd] = __builtin_amdgcn_mfma_f32_16x16x32_bf16(pfA0, vf[dd][0], accA[dd], 0, 0, 0);
                accA[dd] = __builtin_amdgcn_mfma_f32_16x16x32_bf16(pfA1, vf[dd][1], accA[dd], 0, 0, 0);
            }
            lAcc = __builtin_amdgcn_mfma_f32_16x16x32_bf16(pfA0, ones, lAcc, 0, 0, 0);
            lAcc = __builtin_amdgcn_mfma_f32_16x16x32_bf16(pfA1, ones, lAcc, 0, 0, 0);
        }
    }

    // epilogue: O = acc / l
#pragma unroll
    for (int r = 0; r < 4; r++) {
        float invA = 1.0f / lAcc[r];
        float invB = 1.0f / lBcc[r];
        int rowA = mA + quad * 4 + r;
        int rowB = mB + quad * 4 + r;
        u16* ypA = Y + (size_t)(b * T_ + rowA) * D_ + h * HD_ + l16;
        u16* ypB = Y + (size_t)(b * T_ + rowB) * D_ + h * HD_ + l16;
#pragma unroll
        for (int dd = 0; dd < 4; dd++) {
            ypA[dd * 16] = f2b(accA[dd][r] * invA);
            ypB[dd * 16] = f2b(accB[dd][r] * invB);
        }
    }
}

// ---------------------------------------------------------------------------
extern "C" void kernel_launch(void* const* d_in, const int* in_sizes, int n_in,
                              void* d_out, int out_size, void* d_ws, size_t ws_size,
                              hipStream_t stream) {
    const float* x    = (const float*)d_in[0];
    const float* Wq   = (const float*)d_in[1];
    const float* Wk   = (const float*)d_in[2];
    const float* Wv   = (const float*)d_in[3];
    const float* Wp   = (const float*)d_in[4];
    const float* gain = (const float*)d_in[5];
    float* out = (float*)d_out;

    u16* xb   = (u16*)d_ws;
    u16* Wcat = xb   + (size_t)M_ * D_;
    u16* Wpb  = Wcat + (size_t)QS_ * D_;
    u16* QKV  = Wpb  + (size_t)D_ * D_;
    u16* Vt   = QKV  + (size_t)M_ * QS_;
    u16* Y    = Vt   + (size_t)M_ * KV_;
    float2* tab = (float2*)(Y + (size_t)M_ * D_);   // 65536 float2 = 512KB

    ropetab<<<256, 256, 0, stream>>>(tab);
    castk<<<(M_ * D_) / 1024, 256, 0, stream>>>(x,  xb,  M_ * D_);
    castk<<<(D_ * D_) / 1024, 256, 0, stream>>>(Wq, Wcat, D_ * D_);
    castk<<<(KV_ * D_) / 1024, 256, 0, stream>>>(Wk, Wcat + (size_t)D_ * D_, KV_ * D_);
    castk<<<(KV_ * D_) / 1024, 256, 0, stream>>>(Wv, Wcat + (size_t)(D_ + KV_) * D_, KV_ * D_);
    castk<<<(D_ * D_) / 1024, 256, 0, stream>>>(Wp, Wpb, D_ * D_);

    gemm128<u16><<<dim3(QS_ / 128, M_ / 128), 256, 0, stream>>>(xb, Wcat, QKV,
                                                                M_, QS_, D_, QS_);

    norm_rope<<<(M_ * H_ + M_ * HKV_) / 4, 256, 0, stream>>>(QKV, gain, tab);
    vtrans<<<(M_ * KV_) / 2048, 256, 0, stream>>>(QKV, Vt);

    flash<<<dim3(16, H_, B_), 256, 0, stream>>>(QKV, Vt, Y);

    gemm128<float><<<dim3(D_ / 128, M_ / 128), 256, 0, stream>>>(Y, Wpb, out,
                                                                 M_, D_, D_, D_);
}

// Round 6
// 179.635 us; speedup vs baseline: 3.0760x; 1.1624x over previous
//
#include <hip/hip_runtime.h>
#include <cstdint>
#include <cstddef>

typedef __attribute__((ext_vector_type(8))) short short8;
typedef __attribute__((ext_vector_type(4))) float floatx4;
typedef __attribute__((ext_vector_type(4))) short short4v;
typedef unsigned short u16;
typedef unsigned int u32;

#define B_   2
#define T_   2048
#define D_   1024
#define H_   16
#define HKV_ 4
#define HD_  64
#define KV_  256
#define M_   4096   // B*T
#define QS_  1536   // fused QKV row stride

#define NX   4194304   // x elems
#define NWQ  1048576
#define NWK  262144
#define NWV  262144
#define NWP  1048576
#define NCAST (NX + NWQ + NWK + NWV + NWP)        // 6815744
#define CAST_BLOCKS (NCAST / 1024)                 // 6656
#define TAB_BLOCKS  256                            // 65536 entries

__device__ __forceinline__ float b2f(u16 u) {
    union { u32 i; float f; } v; v.i = ((u32)u) << 16; return v.f;
}
__device__ __forceinline__ u16 f2b(float f) {
    union { float f; u32 i; } v; v.f = f;
    u32 r = v.i + 0x7FFF + ((v.i >> 16) & 1);
    return (u16)(r >> 16);
}
// pack hi16(a), hi16(b) -> one u32 (truncation-rounded bf16 pair)
__device__ __forceinline__ u32 pack_hi(float a, float b) {
    union { float f; u32 u; } ua, ub; ua.f = a; ub.f = b;
    return (ua.u >> 16) | (ub.u & 0xFFFF0000u);
}

// async global->LDS, 16 bytes per lane (global_load_lds_dwordx4)
__device__ __forceinline__ void async16(const u16* g, u16* l) {
    __builtin_amdgcn_global_load_lds(
        (const __attribute__((address_space(1))) u32*)g,
        (__attribute__((address_space(3))) u32*)l, 16, 0, 0);
}

// ---------------------------------------------------------------------------
// prep: all fp32->bf16 casts (x, Wq, Wk, Wv, Wp -> contiguous bf16 ws block)
// plus the RoPE cos/sin table. Segment boundaries are block-aligned.
// ---------------------------------------------------------------------------
__global__ __launch_bounds__(256) void prep(const float* __restrict__ x,
                                            const float* __restrict__ wq,
                                            const float* __restrict__ wk,
                                            const float* __restrict__ wv,
                                            const float* __restrict__ wp,
                                            u16* __restrict__ dst,
                                            float2* __restrict__ tab) {
    int blk = blockIdx.x;
    if (blk < CAST_BLOCKS) {
        int i = blk * 1024 + threadIdx.x * 4;
        const float* src; int off;
        if      (i < NX)                  { src = x;  off = i; }
        else if (i < NX+NWQ)              { src = wq; off = i - NX; }
        else if (i < NX+NWQ+NWK)          { src = wk; off = i - (NX+NWQ); }
        else if (i < NX+NWQ+NWK+NWV)      { src = wv; off = i - (NX+NWQ+NWK); }
        else                              { src = wp; off = i - (NX+NWQ+NWK+NWV); }
        float4 v = *(const float4*)(src + off);
        short4v o;
        o.x = (short)f2b(v.x); o.y = (short)f2b(v.y);
        o.z = (short)f2b(v.z); o.w = (short)f2b(v.w);
        *(short4v*)(dst + i) = o;
    } else {
        int idx = (blk - CAST_BLOCKS) * 256 + threadIdx.x;   // 0..65535
        int t = idx >> 5, i = idx & 31;
        float freq = exp2f(-(float)i * (13.287712379549449f / 32.0f)); // 10000^(-i/32)
        float ang = (float)t * freq;
        tab[idx] = make_float2(cosf(ang), sinf(ang));
    }
}

// ---------------------------------------------------------------------------
// QKV GEMM with fused epilogue: RMSNorm + RoPE + q_gain*log2e/8 for Q/K cols,
// direct transposed scatter to Vt for V cols. C row stride QS_.
// m97 structure: 128x128 tile, BK=32, 4 waves, global_load_lds width=16.
// ---------------------------------------------------------------------------
__global__ __launch_bounds__(256) void gemm_qkv(const u16* __restrict__ A,
                                                const u16* __restrict__ W,
                                                u16* __restrict__ C,
                                                u16* __restrict__ Vt,
                                                const float* __restrict__ gain,
                                                const float2* __restrict__ tab) {
    const int K = D_;
    __shared__ u16 As[128 * 32];
    __shared__ u16 Bs[128 * 32];
    const int t = threadIdx.x;
    const int wave = t >> 6, lane = t & 63;
    const int quad = lane >> 4, l16 = lane & 15;
    const int wm = (wave >> 1) * 64, wn = (wave & 1) * 64;
    const int m0 = blockIdx.y * 128, n0 = blockIdx.x * 128;

    floatx4 acc[4][4];
#pragma unroll
    for (int i = 0; i < 4; i++)
#pragma unroll
        for (int j = 0; j < 4; j++) acc[i][j] = (floatx4){0.f, 0.f, 0.f, 0.f};

    const int sr = t >> 2, sc = (t & 3) * 8;
    const u16* ga = A + (size_t)(m0 + sr) * K + sc;
    const u16* gb = W + (size_t)(n0 + sr) * K + sc;
    u16* lA = As + t * 8;
    u16* lB = Bs + t * 8;

    async16(ga, lA);
    async16(ga + (size_t)64 * K, lA + 64 * 32);
    async16(gb, lB);
    async16(gb + (size_t)64 * K, lB + 64 * 32);

    for (int kt = 0; kt < K; kt += 32) {
        __syncthreads();
        short8 af[4], bf[4];
#pragma unroll
        for (int mt = 0; mt < 4; mt++)
            af[mt] = *(const short8*)(As + (wm + mt * 16 + l16) * 32 + quad * 8);
#pragma unroll
        for (int nt = 0; nt < 4; nt++)
            bf[nt] = *(const short8*)(Bs + (wn + nt * 16 + l16) * 32 + quad * 8);
#pragma unroll
        for (int mt = 0; mt < 4; mt++)
#pragma unroll
            for (int nt = 0; nt < 4; nt++)
                acc[mt][nt] = __builtin_amdgcn_mfma_f32_16x16x32_bf16(
                    af[mt], bf[nt], acc[mt][nt], 0, 0, 0);
        __syncthreads();
        if (kt + 32 < K) {
            const u16* ga2 = ga + kt + 32;
            const u16* gb2 = gb + kt + 32;
            async16(ga2, lA);
            async16(ga2 + (size_t)64 * K, lA + 64 * 32);
            async16(gb2, lB);
            async16(gb2 + (size_t)64 * K, lB + 64 * 32);
        }
    }

    const int col0 = n0 + wn;          // 64-aligned: exactly one head-block
    if (col0 < 1280) {
        // ---- Q or K: RMSNorm + RoPE fused on fp32 accumulators ----
        float gs = (col0 < 1024)
                 ? gain[col0 >> 6] * (0.125f * 1.4426950408889634f)  // gain/8*log2e
                 : 1.0f;
#pragma unroll
        for (int mt = 0; mt < 4; mt++)
#pragma unroll
            for (int r = 0; r < 4; r++) {
                int row = m0 + wm + mt * 16 + quad * 4 + r;
                int tt = row & (T_ - 1);
                float v0 = acc[mt][0][r], v1 = acc[mt][1][r];
                float v2 = acc[mt][2][r], v3 = acc[mt][3][r];
                float ss = v0 * v0 + v1 * v1 + v2 * v2 + v3 * v3;
                ss += __shfl_xor(ss, 1); ss += __shfl_xor(ss, 2);
                ss += __shfl_xor(ss, 4); ss += __shfl_xor(ss, 8);
                float inv = rsqrtf(ss * (1.0f / 64.0f) + 1.1920929e-7f);
                v0 *= inv; v1 *= inv; v2 *= inv; v3 *= inv;
                float2 cs0 = tab[tt * 32 + l16];
                float2 cs1 = tab[tt * 32 + 16 + l16];
                float o0 = (v0 * cs0.x + v2 * cs0.y) * gs;
                float o1 = (v1 * cs1.x + v3 * cs1.y) * gs;
                float o2 = (v2 * cs0.x - v0 * cs0.y) * gs;
                float o3 = (v3 * cs1.x - v1 * cs1.y) * gs;
                u16* cp = C + (size_t)row * QS_ + col0 + l16;
                cp[0]  = f2b(o0);
                cp[16] = f2b(o1);
                cp[32] = f2b(o2);
                cp[48] = f2b(o3);
            }
    } else {
        // ---- V: transposed scatter into Vt[(b*4+g)*64 + d][t] ----
        const int g = (col0 - 1280) >> 6;
#pragma unroll
        for (int mt = 0; mt < 4; mt++)
#pragma unroll
            for (int r = 0; r < 4; r++) {
                int row = m0 + wm + mt * 16 + quad * 4 + r;
                int tt = row & (T_ - 1);
                int bb = row >> 11;
#pragma unroll
                for (int nt = 0; nt < 4; nt++)
                    Vt[(size_t)((bb * 4 + g) * 64 + nt * 16 + l16) * T_ + tt] =
                        f2b(acc[mt][nt][r]);
            }
    }
}

// ---------------------------------------------------------------------------
// generic m97-style GEMM (used for the output projection, fp32 out)
// ---------------------------------------------------------------------------
template <typename OutT>
__global__ __launch_bounds__(256) void gemm128(const u16* __restrict__ A,
                                               const u16* __restrict__ W,
                                               OutT* __restrict__ C,
                                               int M, int N, int K, int ldc) {
    __shared__ u16 As[128 * 32];
    __shared__ u16 Bs[128 * 32];
    const int t = threadIdx.x;
    const int wave = t >> 6, lane = t & 63;
    const int quad = lane >> 4, l16 = lane & 15;
    const int wm = (wave >> 1) * 64, wn = (wave & 1) * 64;
    const int m0 = blockIdx.y * 128, n0 = blockIdx.x * 128;

    floatx4 acc[4][4];
#pragma unroll
    for (int i = 0; i < 4; i++)
#pragma unroll
        for (int j = 0; j < 4; j++) acc[i][j] = (floatx4){0.f, 0.f, 0.f, 0.f};

    const int sr = t >> 2, sc = (t & 3) * 8;
    const u16* ga = A + (size_t)(m0 + sr) * K + sc;
    const u16* gb = W + (size_t)(n0 + sr) * K + sc;
    u16* lA = As + t * 8;
    u16* lB = Bs + t * 8;

    async16(ga, lA);
    async16(ga + (size_t)64 * K, lA + 64 * 32);
    async16(gb, lB);
    async16(gb + (size_t)64 * K, lB + 64 * 32);

    for (int kt = 0; kt < K; kt += 32) {
        __syncthreads();
        short8 af[4], bf[4];
#pragma unroll
        for (int mt = 0; mt < 4; mt++)
            af[mt] = *(const short8*)(As + (wm + mt * 16 + l16) * 32 + quad * 8);
#pragma unroll
        for (int nt = 0; nt < 4; nt++)
            bf[nt] = *(const short8*)(Bs + (wn + nt * 16 + l16) * 32 + quad * 8);
#pragma unroll
        for (int mt = 0; mt < 4; mt++)
#pragma unroll
            for (int nt = 0; nt < 4; nt++)
                acc[mt][nt] = __builtin_amdgcn_mfma_f32_16x16x32_bf16(
                    af[mt], bf[nt], acc[mt][nt], 0, 0, 0);
        __syncthreads();
        if (kt + 32 < K) {
            const u16* ga2 = ga + kt + 32;
            const u16* gb2 = gb + kt + 32;
            async16(ga2, lA);
            async16(ga2 + (size_t)64 * K, lA + 64 * 32);
            async16(gb2, lB);
            async16(gb2 + (size_t)64 * K, lB + 64 * 32);
        }
    }

#pragma unroll
    for (int mt = 0; mt < 4; mt++)
#pragma unroll
        for (int nt = 0; nt < 4; nt++)
#pragma unroll
            for (int r = 0; r < 4; r++) {
                int row = m0 + wm + mt * 16 + quad * 4 + r;
                int col = n0 + wn + nt * 16 + l16;
                float val = acc[mt][nt][r];
                if constexpr (sizeof(OutT) == 4) C[(size_t)row * ldc + col] = val;
                else                             C[(size_t)row * ldc + col] = (OutT)f2b(val);
            }
}

// ---------------------------------------------------------------------------
// Flash attention (causal), no-max softmax via v_exp_f32 (log2e in Q gain).
// Complementary q-tile pair (xp, 31-xp) per block: uniform 33 tile-units.
// K/V staged via global_load_lds (XOR-swizzled); S^T trick for packed P write.
// ---------------------------------------------------------------------------
__global__ __launch_bounds__(256) void flash(const u16* __restrict__ QKV,
                                             const u16* __restrict__ Vtr,
                                             u16* __restrict__ Y) {
    const int xp = blockIdx.x;      // 0..15
    const int h  = blockIdx.y;
    const int b  = blockIdx.z;
    const int g  = h >> 2;
    const int w    = threadIdx.x >> 6;
    const int lane = threadIdx.x & 63;
    const int quad = lane >> 4, l16 = lane & 15;

    __shared__ u16 Kt[64 * 64];
    __shared__ u16 Vs[64 * 64];
    __shared__ __align__(16) u16 P[4][2][16][72];

    const int mA = xp * 64 + w * 16;
    const int mB = (31 - xp) * 64 + w * 16;
    const int nA = xp + 1;
    const int nB = 32 - xp;

    const u16* qpA = QKV + (size_t)(b * T_ + mA + l16) * QS_ + h * HD_ + quad * 8;
    const u16* qpB = QKV + (size_t)(b * T_ + mB + l16) * QS_ + h * HD_ + quad * 8;
    short8 aqA0 = *(const short8*)(qpA);
    short8 aqA1 = *(const short8*)(qpA + 32);
    short8 aqB0 = *(const short8*)(qpB);
    short8 aqB1 = *(const short8*)(qpB + 32);

    short8 ones;
#pragma unroll
    for (int i = 0; i < 8; i++) ones[i] = (short)0x3F80;  // bf16 1.0

    floatx4 accA[4], accB[4];
#pragma unroll
    for (int i = 0; i < 4; i++) {
        accA[i] = (floatx4){0.f, 0.f, 0.f, 0.f};
        accB[i] = (floatx4){0.f, 0.f, 0.f, 0.f};
    }
    floatx4 lAcc = (floatx4){0.f, 0.f, 0.f, 0.f};
    floatx4 lBcc = (floatx4){0.f, 0.f, 0.f, 0.f};

    const int srow = w * 16 + (lane >> 3);
    const int sseg = (lane & 7) ^ ((lane >> 3) & 7);
    const u16* kg = QKV + (size_t)(b * T_ + srow) * QS_ + D_ + g * 64 + sseg * 8;
    const u16* vg = Vtr + (size_t)((b * 4 + g) * 64 + srow) * T_ + sseg * 8;
    u16* klds = Kt + w * 1024 + lane * 8;
    u16* vlds = Vs + w * 1024 + lane * 8;

    const int sw0 = (quad ^ (l16 & 7)) * 8;
    const int sw1 = ((4 + quad) ^ (l16 & 7)) * 8;

    async16(kg, klds);
    async16(kg + (size_t)8 * QS_, klds + 512);
    async16(vg, vlds);
    async16(vg + (size_t)8 * T_, vlds + 512);

    for (int tk = 0; tk < nB; tk++) {
        const bool dual = (tk < nA);
        __syncthreads();

        floatx4 SB[4], SA[4];
#pragma unroll
        for (int nt = 0; nt < 4; nt++) {
            const u16* kr = Kt + (nt * 16 + l16) * 64;
            short8 kf0 = *(const short8*)(kr + sw0);
            short8 kf1 = *(const short8*)(kr + sw1);
            SB[nt] = (floatx4){0.f, 0.f, 0.f, 0.f};
            SB[nt] = __builtin_amdgcn_mfma_f32_16x16x32_bf16(kf0, aqB0, SB[nt], 0, 0, 0);
            SB[nt] = __builtin_amdgcn_mfma_f32_16x16x32_bf16(kf1, aqB1, SB[nt], 0, 0, 0);
            if (dual) {
                SA[nt] = (floatx4){0.f, 0.f, 0.f, 0.f};
                SA[nt] = __builtin_amdgcn_mfma_f32_16x16x32_bf16(kf0, aqA0, SA[nt], 0, 0, 0);
                SA[nt] = __builtin_amdgcn_mfma_f32_16x16x32_bf16(kf1, aqA1, SA[nt], 0, 0, 0);
            }
        }
        short8 vf[4][2];
#pragma unroll
        for (int dd = 0; dd < 4; dd++) {
            const u16* vr = Vs + (dd * 16 + l16) * 64;
            vf[dd][0] = *(const short8*)(vr + sw0);
            vf[dd][1] = *(const short8*)(vr + sw1);
        }
        __syncthreads();
        if (tk + 1 < nB) {
            kg += (size_t)64 * QS_;
            vg += 64;
            async16(kg, klds);
            async16(kg + (size_t)8 * QS_, klds + 512);
            async16(vg, vlds);
            async16(vg + (size_t)8 * T_, vlds + 512);
        }

        const bool maskB = (tk == nB - 1);
        const int qB = mB + l16;
#pragma unroll
        for (int nt = 0; nt < 4; nt++) {
            float p[4];
#pragma unroll
            for (int r = 0; r < 4; r++) {
                float e = __builtin_amdgcn_exp2f(SB[nt][r]);
                if (maskB) {
                    int key = tk * 64 + nt * 16 + quad * 4 + r;
                    e = (key <= qB) ? e : 0.f;
                }
                p[r] = e;
            }
            uint2 pw; pw.x = pack_hi(p[0], p[1]); pw.y = pack_hi(p[2], p[3]);
            *(uint2*)&P[w][1][l16][nt * 16 + quad * 4] = pw;
        }
        short8 pfB0 = *(const short8*)&P[w][1][l16][quad * 8];
        short8 pfB1 = *(const short8*)&P[w][1][l16][quad * 8 + 32];
#pragma unroll
        for (int dd = 0; dd < 4; dd++) {
            accB[dd] = __builtin_amdgcn_mfma_f32_16x16x32_bf16(pfB0, vf[dd][0], accB[dd], 0, 0, 0);
            accB[dd] = __builtin_amdgcn_mfma_f32_16x16x32_bf16(pfB1, vf[dd][1], accB[dd], 0, 0, 0);
        }
        lBcc = __builtin_amdgcn_mfma_f32_16x16x32_bf16(pfB0, ones, lBcc, 0, 0, 0);
        lBcc = __builtin_amdgcn_mfma_f32_16x16x32_bf16(pfB1, ones, lBcc, 0, 0, 0);

        if (dual) {
            const bool maskA = (tk == nA - 1);
            const int qA = mA + l16;
#pragma unroll
            for (int nt = 0; nt < 4; nt++) {
                float p[4];
#pragma unroll
                for (int r = 0; r < 4; r++) {
                    float e = __builtin_amdgcn_exp2f(SA[nt][r]);
                    if (maskA) {
                        int key = tk * 64 + nt * 16 + quad * 4 + r;
                        e = (key <= qA) ? e : 0.f;
                    }
                    p[r] = e;
                }
                uint2 pw; pw.x = pack_hi(p[0], p[1]); pw.y = pack_hi(p[2], p[3]);
                *(uint2*)&P[w][0][l16][nt * 16 + quad * 4] = pw;
            }
            short8 pfA0 = *(const short8*)&P[w][0][l16][quad * 8];
            short8 pfA1 = *(const short8*)&P[w][0][l16][quad * 8 + 32];
#pragma unroll
            for (int dd = 0; dd < 4; dd++) {
                accA[dd] = __builtin_amdgcn_mfma_f32_16x16x32_bf16(pfA0, vf[dd][0], accA[dd], 0, 0, 0);
                accA[dd] = __builtin_amdgcn_mfma_f32_16x16x32_bf16(pfA1, vf[dd][1], accA[dd], 0, 0, 0);
            }
            lAcc = __builtin_amdgcn_mfma_f32_16x16x32_bf16(pfA0, ones, lAcc, 0, 0, 0);
            lAcc = __builtin_amdgcn_mfma_f32_16x16x32_bf16(pfA1, ones, lAcc, 0, 0, 0);
        }
    }

#pragma unroll
    for (int r = 0; r < 4; r++) {
        float invA = 1.0f / lAcc[r];
        float invB = 1.0f / lBcc[r];
        int rowA = mA + quad * 4 + r;
        int rowB = mB + quad * 4 + r;
        u16* ypA = Y + (size_t)(b * T_ + rowA) * D_ + h * HD_ + l16;
        u16* ypB = Y + (size_t)(b * T_ + rowB) * D_ + h * HD_ + l16;
#pragma unroll
        for (int dd = 0; dd < 4; dd++) {
            ypA[dd * 16] = f2b(accA[dd][r] * invA);
            ypB[dd * 16] = f2b(accB[dd][r] * invB);
        }
    }
}

// ---------------------------------------------------------------------------
extern "C" void kernel_launch(void* const* d_in, const int* in_sizes, int n_in,
                              void* d_out, int out_size, void* d_ws, size_t ws_size,
                              hipStream_t stream) {
    const float* x    = (const float*)d_in[0];
    const float* Wq   = (const float*)d_in[1];
    const float* Wk   = (const float*)d_in[2];
    const float* Wv   = (const float*)d_in[3];
    const float* Wp   = (const float*)d_in[4];
    const float* gain = (const float*)d_in[5];
    float* out = (float*)d_out;

    u16* xb   = (u16*)d_ws;                      // 4M elems
    u16* Wcat = xb + (size_t)NX;                 // 1.5M (q,k,v rows contiguous)
    u16* Wpb  = Wcat + (size_t)(NWQ + NWK + NWV);// 1M
    u16* QKV  = Wpb + (size_t)NWP;               // 4096 x 1536
    u16* Vt   = QKV + (size_t)M_ * QS_;          // 1M (transposed V)
    u16* Y    = Vt + (size_t)M_ * KV_;           // 4M
    float2* tab = (float2*)(Y + (size_t)M_ * D_);// 65536 float2

    prep<<<CAST_BLOCKS + TAB_BLOCKS, 256, 0, stream>>>(x, Wq, Wk, Wv, Wp, xb, tab);

    gemm_qkv<<<dim3(QS_ / 128, M_ / 128), 256, 0, stream>>>(xb, Wcat, QKV, Vt,
                                                            gain, tab);

    flash<<<dim3(16, H_, B_), 256, 0, stream>>>(QKV, Vt, Y);

    gemm128<float><<<dim3(D_ / 128, M_ / 128), 256, 0, stream>>>(Y, Wpb, out,
                                                                 M_, D_, D_, D_);
}